// Round 8
// baseline (342.133 us; speedup 1.0000x reference)
//
#include <hip/hip_runtime.h>

#define LVAL 256
#define T    32
#define ST   36          // slab row stride (floats): 144 B, 16B-aligned
#define SLAB (T * ST)
#define NB   8
#define NEG  (-1e30f)

typedef float f32x4 __attribute__((ext_vector_type(4)));

#define SOFT_FENCE() asm volatile("" ::: "memory")

__device__ __forceinline__ size_t sidx(int b, int i, int e) {
    return ((size_t)b << 16) + (i << 8) + e;
}

// ---- coherent (MALL-level) accesses for cross-block data: bypass L1/L2 ----
__device__ __forceinline__ void st_coh4(float* p, f32x4 v) {
    asm volatile("global_store_dwordx4 %0, %1, off sc0 sc1"
                 :: "v"(p), "v"(v) : "memory");
}
__device__ __forceinline__ f32x4 ld_coh4_nw(const float* p) {   // no embedded wait
    f32x4 v;
    asm volatile("global_load_dwordx4 %0, %1, off sc0 sc1"
                 : "=&v"(v) : "v"(p) : "memory");
    return v;
}
__device__ __forceinline__ void st_coh1(int* p, int v) {
    asm volatile("global_store_dword %0, %1, off sc0 sc1"
                 :: "v"(p), "v"(v) : "memory");
}
__device__ __forceinline__ int ld_coh1(const int* p) {
    int v;
    asm volatile("global_load_dword %0, %1, off sc0 sc1\n\t"
                 "s_waitcnt vmcnt(0)"
                 : "=&v"(v) : "v"(p) : "memory");
    return v;
}
__device__ __forceinline__ void spin_flag(int* f) {
    int guard = 0;
    while (ld_coh1(f) == 0) {
        if (++guard > (1 << 20)) break;        // fail loudly, never hang
    }
}

// VALU cross-lane max via DPP
template<int CTRL>
__device__ __forceinline__ float dpp_max(float v) {
#if __has_builtin(__builtin_amdgcn_mov_dpp)
    int o = __builtin_amdgcn_mov_dpp(__builtin_bit_cast(int, v), CTRL, 0xF, 0xF, true);
    return fmaxf(v, __builtin_bit_cast(float, o));
#else
    return fmaxf(v, __shfl_xor(v, CTRL == 0xB1 ? 1 : 2));
#endif
}
// octet combine: row_shl:4 -> lane i reads lane i+4 (ISA: "copy from higher
// lane in row"). Writer lanes (q==0,1 -> row-lane 0,1,8,9) always in-row-valid.
__device__ __forceinline__ float dpp_max_shl4(float v) {
#if __has_builtin(__builtin_amdgcn_mov_dpp)
    int o = __builtin_amdgcn_mov_dpp(__builtin_bit_cast(int, v), 0x104, 0xF, 0xF, true);
    return fmaxf(v, __builtin_bit_cast(float, o));
#else
    return fmaxf(v, __shfl_xor(v, 4));
#endif
}

__device__ __forceinline__ float red4(const f32x4 a, const f32x4 b) {
    float m0 = fmaxf(a.x + b.x, a.y + b.y);
    float m1 = fmaxf(a.z + b.z, a.w + b.w);
    return fmaxf(m0, m1);
}

// Phase 1: t[b,i,e] = max_c scores[b,i,e,c] -> f32 s[b][i][e], strict upper only.
__global__ __launch_bounds__(256) void phase1(const float* __restrict__ scores,
                                              float* __restrict__ s,
                                              int* __restrict__ bar) {
    if (blockIdx.x == 0 && blockIdx.y == 0) {
        for (int k = threadIdx.x; k < 2048; k += 256) bar[k] = 0;
    }
    const int i = blockIdx.x, b = blockIdx.y;
    const int sub = threadIdx.x & 15, slot = threadIdx.x >> 4;
    const float* row = scores + ((((size_t)b * LVAL + i) * LVAL) << 6);
    #pragma unroll 4
    for (int m0 = 0; m0 < LVAL; m0 += 16) {
        const int e = m0 + slot;
        if (e > i) {
            float4 v = *((const float4*)(row + ((size_t)e << 6)) + sub);
            float mx = fmaxf(fmaxf(v.x, v.y), fmaxf(v.z, v.w));
            #pragma unroll
            for (int d = 1; d < 16; d <<= 1) mx = fmaxf(mx, __shfl_xor(mx, d));
            if (sub == 0) s[sidx(b, i, e)] = mx;
        }
    }
}

// Octet diag step (round 0): 8 lanes per cell, all 4 waves, barrier-per-step.
__device__ __forceinline__ void diag_step8(int tid, int l,
        float (*cur0)[ST], float (*curT0)[ST], const float (*t0)[ST]) {
    const int cells = T - l;
    const int oct = tid >> 3, q = tid & 7;
    const bool g = oct < cells;
    const int li = g ? oct : 0;
    const int le = g ? oct + l : 0;
    const int k0 = q * 4;
    f32x4 x = *(const f32x4*)&cur0[li][k0];
    f32x4 y = *(const f32x4*)&curT0[le][k0];
    const float tv = t0[li][le];
    float acc = red4(x, y);
    acc = dpp_max<0xB1>(acc);
    acc = dpp_max<0x4E>(acc);
    acc = dpp_max_shl4(acc);
    const float v = acc + tv;
    if (g && q == 0) cur0[li][le] = v;
    if (g && q == 1) curT0[le][li] = v;
}

// Octet edge step (round D): 8 lanes per cell. q<4: product A (Ae x curT),
// q>=4: product B (cur x BeT); each lane 2 chunk-pairs (4 ds_read_b128).
__device__ __forceinline__ void edge_step8(int tid, int l, int D,
        const float (*Ae)[ST], const float (*BeT)[ST],
        float (*cur)[ST], float (*curT)[ST],
        const float (*tb)[ST], const float (*pre)[ST]) {
    const int delta = l - (T - 1);
    const int ad = delta < 0 ? -delta : delta;
    const int cells = T - ad;
    const int oct = tid >> 3, q = tid & 7;
    const bool g = oct < cells;
    const int li = g ? (delta < 0 ? oct + ad : oct) : 0;
    const int le = g ? li + delta : 0;
    const int k0 = (q & 3) * 8;
    const float* r1 = (q < 4) ? &Ae[li][0]   : &cur[li][0];
    const float* r2 = (q < 4) ? &curT[le][0] : &BeT[le][0];
    f32x4 x0 = *(const f32x4*)&r1[k0];
    f32x4 y0 = *(const f32x4*)&r2[k0];
    f32x4 x1 = *(const f32x4*)&r1[k0 + 4];
    f32x4 y1 = *(const f32x4*)&r2[k0 + 4];
    const float tv = tb[li][le];
    const float pr = pre[li][le];
    float local = fmaxf(red4(x0, y0), red4(x1, y1));
    local = fmaxf(local, pr);                  // idempotent: include in all lanes
    float acc = dpp_max<0xB1>(local);
    acc = dpp_max<0x4E>(acc);
    acc = dpp_max_shl4(acc);
    const float v = (D == 1 && l == 0) ? tv : acc + tv;
    if (g && q == 0) cur[li][le] = v;
    if (g && q == 1) curT[le][li] = v;
}

// (max,+) GEMM of one 32x32 K-block
__device__ __forceinline__ void gemm_blk(const float* ATs, const float (*BW)[ST],
                                         int r0, int c0, float (&ag)[4][4]) {
    const float (*AT)[ST] = (const float(*)[ST])ATs;
    #pragma unroll 4
    for (int k = 0; k < T; ++k) {
        f32x4 a4 = *(const f32x4*)&AT[k][r0];
        f32x4 b4 = *(const f32x4*)&BW[k][c0];
        #pragma unroll
        for (int i = 0; i < 4; ++i)
            #pragma unroll
            for (int j = 0; j < 4; ++j)
                ag[i][j] = fmaxf(ag[i][j], a4[i] + b4[j]);
    }
}

// Self-timed dataflow (r7 skeleton): per-tile flags, no global barrier.
__global__ __launch_bounds__(256) void dp_fused(float* __restrict__ s,
                                                const int* __restrict__ lens,
                                                float* __restrict__ out,
                                                int* __restrict__ bar) {
    __shared__ __align__(16) float smem[14 * SLAB];      // 64512 B
    float* ATb = smem;                                   // 6 persistent A^T slabs
    float (*Ae)[ST]  = (float(*)[ST])(smem + 6 * SLAB);
    float (*tb)[ST]  = (float(*)[ST])(smem + 7 * SLAB);
    float (*BeT)[ST] = (float(*)[ST])(smem + 8 * SLAB);
    float (*cur)[ST] = (float(*)[ST])(smem + 9 * SLAB);
    float* BWb = smem + 10 * SLAB;                       // 4 per-wave GEMM slabs
    float (*pre)[ST] = (float(*)[ST])BWb;                // = BW0 (after combine)

    const int b  = blockIdx.x & 7;
    const int bi = blockIdx.x >> 3;
    const int tid = threadIdx.x, wid = tid >> 6, lane = tid & 63;
    const int lr = tid >> 5, lc = tid & 31;
    const int grow = lane >> 1, gc = (lane & 1) * 16;
    const int gly = lane >> 3, glx = lane & 7, r0 = 4 * gly, c0 = 4 * glx;
    const int trow = tid >> 3, tc4 = (tid & 7) * 4;
    float (*BW)[ST] = (float(*)[ST])(BWb + wid * SLAB);
    int* flags = bar + b * 64;                 // flags[K*8 + e] per tile (K,e)

    // ---- round 0: octet diag DP into Ae (all 4 waves); tb(D=1) staged too
    {
        float (*curT0)[ST] = (float(*)[ST])(BWb + 1 * SLAB);
        float (*t0)[ST]    = (float(*)[ST])(BWb + 2 * SLAB);
        const f32x4 negv = {NEG, NEG, NEG, NEG};
        f32x4 v = *(const f32x4*)&s[sidx(b, bi * T + trow, bi * T + tc4)];
        *(f32x4*)&t0[trow][tc4]    = v;
        *(f32x4*)&Ae[trow][tc4]    = negv;
        *(f32x4*)&curT0[trow][tc4] = negv;
        if (bi + 1 < NB) {
            f32x4 w = *(const f32x4*)&s[sidx(b, bi * T + trow, (bi + 1) * T + tc4)];
            *(f32x4*)&tb[trow][tc4] = w;
        }
        __syncthreads();
        if (tid < T - 1) {                     // w == 1 diagonal = t (final)
            float d = t0[tid][tid + 1];
            Ae[tid][tid + 1] = d;
            curT0[tid + 1][tid] = d;
        }
        __syncthreads();
        #pragma unroll 1
        for (int l = 2; l < T; ++l) {
            diag_step8(tid, l, Ae, curT0, t0);
            __syncthreads();
        }
        st_coh4(&s[sidx(b, bi * T + trow, bi * T + tc4)],
                *(const f32x4*)&Ae[trow][tc4]);
        asm volatile("s_waitcnt vmcnt(0)" ::: "memory");
        __syncthreads();
        if (tid == 0) st_coh1(&flags[bi * 8 + bi], 1);   // release diag tile
    }

    // ---- rounds 1..NB-1-bi (blocks exit when their row is done) ----
    #pragma unroll 1
    for (int D = 1; D <= NB - 1 - bi; ++D) {
        const int be = bi + D;
        if (tid == 0) {                        // wait exactly what we consume
            spin_flag(&flags[be * 8 + be]);    // diag (set at round 0)
            for (int K = be - 1; K >= bi + 1; --K) spin_flag(&flags[K * 8 + be]);
        }
        __syncthreads();
        // unified no-wait coherent loads, one vmcnt drain
        f32x4 dg = ld_coh4_nw(&s[sidx(b, be * T + trow, be * T + tc4)]);
        f32x4 tbv = *(const f32x4*)&s[sidx(b, bi * T + trow, be * T + tc4)];
        const int KA = bi + 1 + wid, KB = bi + 5 + wid;
        const bool hA = (KA < be), hB = (KB < be);
        f32x4 a0, a1, a2, a3, bb0, bb1, bb2, bb3;
        if (hA) {
            const float* p = &s[sidx(b, KA * T + grow, be * T + gc)];
            a0 = ld_coh4_nw(p);     a1 = ld_coh4_nw(p + 4);
            a2 = ld_coh4_nw(p + 8); a3 = ld_coh4_nw(p + 12);
        }
        if (hB) {
            const float* p = &s[sidx(b, KB * T + grow, be * T + gc)];
            bb0 = ld_coh4_nw(p);     bb1 = ld_coh4_nw(p + 4);
            bb2 = ld_coh4_nw(p + 8); bb3 = ld_coh4_nw(p + 12);
        }
        asm volatile("s_waitcnt vmcnt(0)" ::: "memory");
        BeT[tc4 + 0][trow] = (trow < tc4 + 0) ? dg[0] : NEG;
        BeT[tc4 + 1][trow] = (trow < tc4 + 1) ? dg[1] : NEG;
        BeT[tc4 + 2][trow] = (trow < tc4 + 2) ? dg[2] : NEG;
        BeT[tc4 + 3][trow] = (trow < tc4 + 3) ? dg[3] : NEG;
        *(f32x4*)&tb[trow][tc4] = tbv;
        // GEMM over middle K blocks (A^T resident in persistent LDS slabs)
        const int nw = (D - 1 < 4) ? (D - 1) : 4;
        float ag[4][4];
        #pragma unroll
        for (int i = 0; i < 4; ++i)
            #pragma unroll
            for (int j = 0; j < 4; ++j) ag[i][j] = NEG;
        if (hA) {
            *(f32x4*)&BW[grow][gc + 0]  = a0;
            *(f32x4*)&BW[grow][gc + 4]  = a1;
            *(f32x4*)&BW[grow][gc + 8]  = a2;
            *(f32x4*)&BW[grow][gc + 12] = a3;
            SOFT_FENCE();
            gemm_blk(ATb + wid * SLAB, BW, r0, c0, ag);
            SOFT_FENCE();
        }
        if (hB) {
            *(f32x4*)&BW[grow][gc + 0]  = bb0;
            *(f32x4*)&BW[grow][gc + 4]  = bb1;
            *(f32x4*)&BW[grow][gc + 8]  = bb2;
            *(f32x4*)&BW[grow][gc + 12] = bb3;
            SOFT_FENCE();
            gemm_blk(ATb + (wid + 4) * SLAB, BW, r0, c0, ag);
        }
        if (wid < nw) {
            #pragma unroll
            for (int i = 0; i < 4; ++i)
                *(f32x4*)&BW[r0 + i][c0] =
                    f32x4{ag[i][0], ag[i][1], ag[i][2], ag[i][3]};
        }
        __syncthreads();
        #pragma unroll
        for (int r = 0; r < 4; ++r) {          // combine wave partials -> pre
            const int row = lr + 8 * r;
            float v = NEG;
            for (int w2 = 0; w2 < nw; ++w2)
                v = fmaxf(v, BWb[w2 * SLAB + row * ST + lc]);
            pre[row][lc] = v;
        }
        __syncthreads();
        float (*curT)[ST] = (D == NB - 1) ? (float(*)[ST])(BWb + 1 * SLAB)
                                          : (float(*)[ST])(ATb + (D - 1) * SLAB);
        #pragma unroll
        for (int r = 0; r < 4; ++r) {
            const int row = lr + 8 * r;
            cur[row][lc]  = NEG;
            curT[row][lc] = NEG;
        }
        __syncthreads();
        // ---- multi-wave octet edge pass: 63 steps, barrier per step
        #pragma unroll 1
        for (int l = 0; l < 2 * T - 1; ++l) {
            edge_step8(tid, l, D, Ae, BeT, cur, curT, tb, pre);
            __syncthreads();
        }
        {                                      // publish (bi,be) for other rows
            f32x4 pv = *(const f32x4*)&cur[trow][tc4];
            st_coh4(&s[sidx(b, bi * T + trow, be * T + tc4)], pv);
        }
        asm volatile("s_waitcnt vmcnt(0)" ::: "memory");
        __syncthreads();
        if (tid == 0) st_coh1(&flags[bi * 8 + be], 1);   // release tile
    }

    // Fused finalize: block (b,0) owns row 0, everything needed is in its LDS.
    if (bi == 0 && tid == 0) {
        int len = lens[b];
        len = len < 1 ? 1 : (len > LVAL - 1 ? LVAL - 1 : len);
        const int K = len >> 5, off = len & 31;
        float r;
        if (K == 0)           r = Ae[0][off];
        else if (K == NB - 1) r = cur[0][off];
        else                  r = ATb[(K - 1) * SLAB + off * ST];
        out[b] = r;
    }
}

extern "C" void kernel_launch(void* const* d_in, const int* in_sizes, int n_in,
                              void* d_out, int out_size, void* d_ws, size_t ws_size,
                              hipStream_t stream) {
    const float* scores = (const float*)d_in[0];
    const int*   lens   = (const int*)d_in[1];
    float*       out    = (float*)d_out;
    float*       s      = (float*)d_ws;               // 8 * 256 * 256 f32 = 2 MB
    int*         bar    = (int*)((char*)d_ws + ((size_t)(8) << 16) * sizeof(float));

    phase1<<<dim3(LVAL, 8), 256, 0, stream>>>(scores, s, bar);
    dp_fused<<<64, 256, 0, stream>>>(s, lens, out, bar);
}